// Round 2
// baseline (348.369 us; speedup 1.0000x reference)
//
#include <hip/hip_runtime.h>
#include <hip/hip_bf16.h>

#define D_MODEL 64
#define D_STATE 16
#define IMG     32
#define HW      (IMG*IMG)      // 1024
#define V       9
#define B       4
#define GROUPS  4
#define CPG     (D_MODEL/GROUPS) // 16

// ---------------- Kernel 1: GroupNorm ----------------
// grid = B*GROUPS blocks, 256 threads
__global__ __launch_bounds__(256) void gn_kernel(
    const float* __restrict__ u, const float* __restrict__ gamma,
    const float* __restrict__ beta, float* __restrict__ un)
{
    const int b = blockIdx.x / GROUPS;
    const int g = blockIdx.x % GROUPS;
    const float* base = u + ((size_t)b*D_MODEL + g*CPG) * HW;
    const int NE = CPG * HW; // 16384

    float s = 0.f, s2 = 0.f;
    for (int i = threadIdx.x; i < NE; i += 256) {
        float v = base[i];
        s += v; s2 += v*v;
    }
    // wave reduce (64-wide)
    for (int off = 32; off; off >>= 1) {
        s  += __shfl_down(s,  off);
        s2 += __shfl_down(s2, off);
    }
    __shared__ float red0[4], red1[4];
    const int wave = threadIdx.x >> 6;
    if ((threadIdx.x & 63) == 0) { red0[wave] = s; red1[wave] = s2; }
    __syncthreads();
    if (threadIdx.x == 0) {
        float a = 0.f, c = 0.f;
        for (int i = 0; i < 4; i++) { a += red0[i]; c += red1[i]; }
        red0[0] = a; red1[0] = c;
    }
    __syncthreads();
    const float mean = red0[0] * (1.f/16384.f);
    const float var  = red1[0] * (1.f/16384.f) - mean*mean;
    const float rstd = rsqrtf(var + 1e-5f);

    for (int i = threadIdx.x; i < NE; i += 256) {
        int c = i >> 10;             // channel within group
        int d = g*CPG + c;
        float v = (base[i] - mean) * rstd;
        un[((size_t)b*D_MODEL + d)*HW + (i & (HW-1))] = v*gamma[d] + beta[d];
    }
}

// ---------------- Kernel 2: A = -exp(log_A_real), 64x16 ----------------
__global__ __launch_bounds__(256) void aneg_kernel(
    const float* __restrict__ logA, float* __restrict__ aneg)
{
    int i = blockIdx.x*256 + threadIdx.x;
    if (i < D_MODEL*D_STATE) aneg[i] = -expf(logA[i]);
}

// ---------------- Kernel 3: circular 3x3 convs (delta / B_val / C_val) ----------------
// grid = B*96 blocks; co<64 -> delta (softplus+clip), 64..79 -> B_val, 80..95 -> C_val
__global__ __launch_bounds__(256) void conv_kernel(
    const float* __restrict__ un,
    const float* __restrict__ w_delta, const float* __restrict__ b_delta,
    const float* __restrict__ w_B, const float* __restrict__ w_C,
    const float* __restrict__ dt_sp,
    float* __restrict__ delta, float* __restrict__ Bv, float* __restrict__ Cv)
{
    const int b  = blockIdx.x / 96;
    const int co = blockIdx.x % 96;

    const float* w; float bias; float* outp; int is_delta = 0;
    if (co < 64) {
        w = w_delta + (size_t)co * (D_MODEL*9);
        bias = b_delta[co] + dt_sp[0];
        outp = delta + ((size_t)b*D_MODEL + co) * HW;
        is_delta = 1;
    } else if (co < 80) {
        w = w_B + (size_t)(co-64) * (D_MODEL*9);
        bias = 0.f;
        outp = Bv + ((size_t)b*D_STATE + (co-64)) * HW;
    } else {
        w = w_C + (size_t)(co-80) * (D_MODEL*9);
        bias = 0.f;
        outp = Cv + ((size_t)b*D_STATE + (co-80)) * HW;
    }

    __shared__ float wl[D_MODEL*9];
    for (int i = threadIdx.x; i < D_MODEL*9; i += 256) wl[i] = w[i];
    __syncthreads();

    const float* x = un + (size_t)b*D_MODEL*HW;

    for (int p = threadIdx.x; p < HW; p += 256) {
        const int oy = p >> 5, ox = p & 31;
        float acc = bias;
        for (int ci = 0; ci < D_MODEL; ci++) {
            const float* xc = x + ci*HW;
            const float* wc = wl + ci*9;
            #pragma unroll
            for (int ky = 0; ky < 3; ky++) {
                const int sy = (oy + ky - 1) & 31;
                #pragma unroll
                for (int kx = 0; kx < 3; kx++) {
                    const int sx = (ox + kx - 1) & 31;
                    acc = fmaf(xc[(sy << 5) | sx], wc[ky*3 + kx], acc);
                }
            }
        }
        if (is_delta) {
            float sp = (acc > 15.f) ? acc : log1pf(__expf(acc));
            sp = fminf(fmaxf(sp, 1e-4f), 5.f);
            outp[p] = sp;
        } else {
            outp[p] = acc;
        }
    }
}

// ---------------- Kernel 4: main fused state update ----------------
// grid = B*V*D_MODEL blocks (2304), 256 threads; thread strides over 1024 spatial pts
__global__ __launch_bounds__(256) void main_kernel(
    const float* __restrict__ sprev, const float* __restrict__ ut,
    const float* __restrict__ delta, const float* __restrict__ Bv,
    const float* __restrict__ Cv, const float* __restrict__ aneg,
    const float* __restrict__ Dp, const int* __restrict__ gidx,
    float* __restrict__ ynew, float* __restrict__ snew)
{
    const int blk = blockIdx.x;              // (b*V + v)*D_MODEL + d
    const int d   = blk % D_MODEL;
    const int tmp = blk / D_MODEL;
    const int v   = tmp % V;
    const int b   = tmp / V;

    const int* gi = gidx + v*HW;
    const size_t bvd = (((size_t)b*V + v)*D_MODEL + d);
    const float* sp_base = sprev + bvd * D_STATE * HW;
    float* sn_base = snew + bvd * D_STATE * HW;
    float* yn_base = ynew + bvd * HW;

    const float dpd = Dp[d];

    float an[D_STATE];
    #pragma unroll
    for (int n = 0; n < D_STATE; n++) an[n] = aneg[d*D_STATE + n];

    const float* dl_row = delta + ((size_t)b*D_MODEL + d)*HW;
    const float* u_row  = ut    + ((size_t)b*D_MODEL + d)*HW;
    const float* Bv_b   = Bv + (size_t)b*D_STATE*HW;
    const float* Cv_b   = Cv + (size_t)b*D_STATE*HW;

    for (int p = threadIdx.x; p < HW; p += 256) {
        const int src = gi[p];
        const float dl = dl_row[p];
        const float u  = u_row[p];
        float y = u * dpd;
        #pragma unroll
        for (int n = 0; n < D_STATE; n++) {
            const float s  = sp_base[n*HW + src];
            const float ab = __expf(dl * an[n]);
            const float bb = dl * Bv_b[n*HW + p];
            const float sn = fmaf(ab, s, bb*u);
            sn_base[n*HW + p] = sn;
            y = fmaf(sn, Cv_b[n*HW + p], y);
        }
        yn_base[p] = y;
    }
}

extern "C" void kernel_launch(void* const* d_in, const int* in_sizes, int n_in,
                              void* d_out, int out_size, void* d_ws, size_t ws_size,
                              hipStream_t stream)
{
    const float* u_t       = (const float*)d_in[0];
    const float* s_prev    = (const float*)d_in[1];
    const float* gamma     = (const float*)d_in[2];
    const float* beta      = (const float*)d_in[3];
    const float* w_delta   = (const float*)d_in[4];
    const float* b_delta   = (const float*)d_in[5];
    const float* w_B       = (const float*)d_in[6];
    const float* w_C       = (const float*)d_in[7];
    const float* log_A     = (const float*)d_in[8];
    const float* D_param   = (const float*)d_in[9];
    const float* dt_sp     = (const float*)d_in[10];
    const int*   gidx      = (const int*)d_in[11];

    // workspace layout (floats)
    float* ws = (float*)d_ws;
    float* un    = ws;                      // B*64*1024      = 262144
    float* delta = un    + (size_t)B*D_MODEL*HW;   // 262144
    float* Bv    = delta + (size_t)B*D_MODEL*HW;   // 65536
    float* Cv    = Bv    + (size_t)B*D_STATE*HW;   // 65536
    float* aneg  = Cv    + (size_t)B*D_STATE*HW;   // 1024

    // outputs: [y_new (B*V*D*HW) | s_new (B*V*D*N*HW)] as f32
    float* ynew = (float*)d_out;
    float* snew = ynew + (size_t)B*V*D_MODEL*HW;

    gn_kernel<<<B*GROUPS, 256, 0, stream>>>(u_t, gamma, beta, un);
    aneg_kernel<<<(D_MODEL*D_STATE + 255)/256, 256, 0, stream>>>(log_A, aneg);
    conv_kernel<<<B*96, 256, 0, stream>>>(un, w_delta, b_delta, w_B, w_C, dt_sp,
                                          delta, Bv, Cv);
    main_kernel<<<B*V*D_MODEL, 256, 0, stream>>>(s_prev, u_t, delta, Bv, Cv,
                                                 aneg, D_param, gidx, ynew, snew);
}

// Round 3
// 135.097 us; speedup vs baseline: 2.5787x; 2.5787x over previous
//
#include <hip/hip_runtime.h>
#include <hip/hip_bf16.h>

#define D_MODEL 64
#define D_STATE 16
#define IMG     32
#define HW      (IMG*IMG)      // 1024
#define V       9
#define B       4
#define GROUPS  4
#define CPG     (D_MODEL/GROUPS) // 16

// ---------------- Kernel 1: GroupNorm ----------------
__global__ __launch_bounds__(256) void gn_kernel(
    const float* __restrict__ u, const float* __restrict__ gamma,
    const float* __restrict__ beta, float* __restrict__ un)
{
    const int b = blockIdx.x / GROUPS;
    const int g = blockIdx.x % GROUPS;
    const float* base = u + ((size_t)b*D_MODEL + g*CPG) * HW;
    const int NE = CPG * HW; // 16384

    float s = 0.f, s2 = 0.f;
    for (int i = threadIdx.x; i < NE; i += 256) {
        float v = base[i];
        s += v; s2 += v*v;
    }
    for (int off = 32; off; off >>= 1) {
        s  += __shfl_down(s,  off);
        s2 += __shfl_down(s2, off);
    }
    __shared__ float red0[4], red1[4];
    const int wave = threadIdx.x >> 6;
    if ((threadIdx.x & 63) == 0) { red0[wave] = s; red1[wave] = s2; }
    __syncthreads();
    if (threadIdx.x == 0) {
        float a = 0.f, c = 0.f;
        for (int i = 0; i < 4; i++) { a += red0[i]; c += red1[i]; }
        red0[0] = a; red1[0] = c;
    }
    __syncthreads();
    const float mean = red0[0] * (1.f/16384.f);
    const float var  = red1[0] * (1.f/16384.f) - mean*mean;
    const float rstd = rsqrtf(var + 1e-5f);

    for (int i = threadIdx.x; i < NE; i += 256) {
        int c = i >> 10;
        int d = g*CPG + c;
        float v = (base[i] - mean) * rstd;
        un[((size_t)b*D_MODEL + d)*HW + (i & (HW-1))] = v*gamma[d] + beta[d];
    }
}

// ---------------- Kernel 2: A = -exp(log_A_real) ----------------
__global__ __launch_bounds__(256) void aneg_kernel(
    const float* __restrict__ logA, float* __restrict__ aneg)
{
    int i = blockIdx.x*256 + threadIdx.x;
    if (i < D_MODEL*D_STATE) aneg[i] = -expf(logA[i]);
}

// ---------------- Kernel 3: circular 3x3 convs, LDS-staged, 4 co / block ----------------
// grid = B * 24 * 4   (24 groups of 4 output chans; 4 strips of 8 rows)
// co 0..63 -> delta (softplus+clip), 64..79 -> B_val, 80..95 -> C_val
__global__ __launch_bounds__(256) void conv_kernel(
    const float* __restrict__ un,
    const float* __restrict__ w_delta, const float* __restrict__ b_delta,
    const float* __restrict__ w_B, const float* __restrict__ w_C,
    const float* __restrict__ dt_sp,
    float* __restrict__ delta, float* __restrict__ Bv, float* __restrict__ Cv)
{
    const int bx    = blockIdx.x;
    const int strip = bx & 3;
    const int cog   = (bx >> 2) % 24;
    const int b     = bx / 96;
    const int co0   = cog * 4;
    const int row0  = strip * 8;

    __shared__ float xs[16][10][32];   // 20 KB: 16 ci x (8 rows + halo) x 32
    __shared__ float wl[4][D_MODEL*9]; // 9.2 KB

    // stage all weights for the 4 output channels
    for (int i = threadIdx.x; i < 4*D_MODEL*9; i += 256) {
        const int cl = i / (D_MODEL*9);
        const int rest = i % (D_MODEL*9);
        const int co = co0 + cl;
        const float* w = (co < 64) ? (w_delta + (size_t)co*(D_MODEL*9))
                       : (co < 80) ? (w_B + (size_t)(co-64)*(D_MODEL*9))
                                   : (w_C + (size_t)(co-80)*(D_MODEL*9));
        wl[cl][rest] = w[rest];
    }

    const int ly = threadIdx.x >> 5;   // 0..7
    const int ox = threadIdx.x & 31;
    const int oy = row0 + ly;

    const float* x = un + (size_t)b*D_MODEL*HW;
    float a0 = 0.f, a1 = 0.f, a2 = 0.f, a3 = 0.f;

    for (int c = 0; c < 4; c++) {
        __syncthreads();
        // stage 16 input channels x 10 rows x 32 cols (coalesced)
        for (int i = threadIdx.x; i < 16*10*32; i += 256) {
            const int ci = i / 320;
            const int rr = (i % 320) >> 5;
            const int xx = i & 31;
            const int gy = (row0 - 1 + rr) & 31;
            xs[ci][rr][xx] = x[(size_t)(c*16 + ci)*HW + (gy << 5) + xx];
        }
        __syncthreads();

        #pragma unroll
        for (int ci = 0; ci < 16; ci++) {
            float v[3][3];
            #pragma unroll
            for (int dy = 0; dy < 3; dy++)
                #pragma unroll
                for (int dx = 0; dx < 3; dx++)
                    v[dy][dx] = xs[ci][ly + dy][(ox + dx + 31) & 31];
            const int cig = c*16 + ci;
            const float* w0 = &wl[0][cig*9];
            const float* w1 = &wl[1][cig*9];
            const float* w2 = &wl[2][cig*9];
            const float* w3 = &wl[3][cig*9];
            #pragma unroll
            for (int t = 0; t < 9; t++) {
                const float xv = v[t/3][t%3];
                a0 = fmaf(xv, w0[t], a0);
                a1 = fmaf(xv, w1[t], a1);
                a2 = fmaf(xv, w2[t], a2);
                a3 = fmaf(xv, w3[t], a3);
            }
        }
    }

    const int p = (oy << 5) + ox;
    const float dtsp = dt_sp[0];
    float accs[4] = {a0, a1, a2, a3};
    #pragma unroll
    for (int cl = 0; cl < 4; cl++) {
        const int co = co0 + cl;
        float acc = accs[cl];
        if (co < 64) {
            acc += b_delta[co] + dtsp;
            float sp = (acc > 15.f) ? acc : log1pf(__expf(acc));
            sp = fminf(fmaxf(sp, 1e-4f), 5.f);
            delta[((size_t)b*D_MODEL + co)*HW + p] = sp;
        } else if (co < 80) {
            Bv[((size_t)b*D_STATE + (co-64))*HW + p] = acc;
        } else {
            Cv[((size_t)b*D_STATE + (co-80))*HW + p] = acc;
        }
    }
}

// ---------------- Kernel 4: main fused state update ----------------
// grid = B*V*D_MODEL blocks (2304), 256 threads; thread handles 4 consecutive pts
__global__ __launch_bounds__(256) void main_kernel(
    const float* __restrict__ sprev, const float* __restrict__ ut,
    const float* __restrict__ delta, const float* __restrict__ Bv,
    const float* __restrict__ Cv, const float* __restrict__ aneg,
    const float* __restrict__ Dp, const int* __restrict__ gidx,
    float* __restrict__ ynew, float* __restrict__ snew)
{
    const int blk = blockIdx.x;              // (b*V + v)*D_MODEL + d
    const int d   = blk % D_MODEL;
    const int tmp = blk / D_MODEL;
    const int v   = tmp % V;
    const int b   = tmp / V;

    const int p0 = threadIdx.x * 4;

    const int4 src4 = *(const int4*)(gidx + v*HW + p0);
    const size_t bvd = (((size_t)b*V + v)*D_MODEL + d);
    const float* sp_base = sprev + bvd * D_STATE * HW;
    float* sn_base = snew + bvd * D_STATE * HW;

    const float dpd = Dp[d];

    float an[D_STATE];
    #pragma unroll
    for (int n = 0; n < D_STATE; n++) an[n] = aneg[d*D_STATE + n];

    const float4 dl = *(const float4*)(delta + ((size_t)b*D_MODEL + d)*HW + p0);
    const float4 uu = *(const float4*)(ut    + ((size_t)b*D_MODEL + d)*HW + p0);
    const float* Bv_b = Bv + (size_t)b*D_STATE*HW + p0;
    const float* Cv_b = Cv + (size_t)b*D_STATE*HW + p0;

    float4 y;
    y.x = uu.x * dpd; y.y = uu.y * dpd; y.z = uu.z * dpd; y.w = uu.w * dpd;

    #pragma unroll
    for (int n = 0; n < D_STATE; n++) {
        const float* sp_n = sp_base + n*HW;
        const float s0 = sp_n[src4.x];
        const float s1 = sp_n[src4.y];
        const float s2 = sp_n[src4.z];
        const float s3 = sp_n[src4.w];
        const float4 Bn = *(const float4*)(Bv_b + n*HW);
        const float4 Cn = *(const float4*)(Cv_b + n*HW);
        float4 sn;
        sn.x = fmaf(__expf(dl.x * an[n]), s0, dl.x * Bn.x * uu.x);
        sn.y = fmaf(__expf(dl.y * an[n]), s1, dl.y * Bn.y * uu.y);
        sn.z = fmaf(__expf(dl.z * an[n]), s2, dl.z * Bn.z * uu.z);
        sn.w = fmaf(__expf(dl.w * an[n]), s3, dl.w * Bn.w * uu.w);
        *(float4*)(sn_base + n*HW + p0) = sn;
        y.x = fmaf(sn.x, Cn.x, y.x);
        y.y = fmaf(sn.y, Cn.y, y.y);
        y.z = fmaf(sn.z, Cn.z, y.z);
        y.w = fmaf(sn.w, Cn.w, y.w);
    }
    *(float4*)(ynew + bvd * HW + p0) = y;
}

extern "C" void kernel_launch(void* const* d_in, const int* in_sizes, int n_in,
                              void* d_out, int out_size, void* d_ws, size_t ws_size,
                              hipStream_t stream)
{
    const float* u_t       = (const float*)d_in[0];
    const float* s_prev    = (const float*)d_in[1];
    const float* gamma     = (const float*)d_in[2];
    const float* beta      = (const float*)d_in[3];
    const float* w_delta   = (const float*)d_in[4];
    const float* b_delta   = (const float*)d_in[5];
    const float* w_B       = (const float*)d_in[6];
    const float* w_C       = (const float*)d_in[7];
    const float* log_A     = (const float*)d_in[8];
    const float* D_param   = (const float*)d_in[9];
    const float* dt_sp     = (const float*)d_in[10];
    const int*   gidx      = (const int*)d_in[11];

    float* ws = (float*)d_ws;
    float* un    = ws;
    float* delta = un    + (size_t)B*D_MODEL*HW;
    float* Bv    = delta + (size_t)B*D_MODEL*HW;
    float* Cv    = Bv    + (size_t)B*D_STATE*HW;
    float* aneg  = Cv    + (size_t)B*D_STATE*HW;

    float* ynew = (float*)d_out;
    float* snew = ynew + (size_t)B*V*D_MODEL*HW;

    gn_kernel<<<B*GROUPS, 256, 0, stream>>>(u_t, gamma, beta, un);
    aneg_kernel<<<(D_MODEL*D_STATE + 255)/256, 256, 0, stream>>>(log_A, aneg);
    conv_kernel<<<B*96, 256, 0, stream>>>(un, w_delta, b_delta, w_B, w_C, dt_sp,
                                          delta, Bv, Cv);
    main_kernel<<<B*V*D_MODEL, 256, 0, stream>>>(s_prev, u_t, delta, Bv, Cv,
                                                 aneg, D_param, gidx, ynew, snew);
}

// Round 5
// 105.161 us; speedup vs baseline: 3.3127x; 1.2847x over previous
//
#include <hip/hip_runtime.h>
#include <hip/hip_bf16.h>

#define D_MODEL 64
#define D_STATE 16
#define IMG     32
#define HW      (IMG*IMG)      // 1024
#define V       9
#define B       4
#define GROUPS  4
#define CPG     (D_MODEL/GROUPS) // 16

typedef float f32x4 __attribute__((ext_vector_type(4)));

__device__ __forceinline__ void nt_store4(float* p, const float4& v) {
    f32x4 t; t.x = v.x; t.y = v.y; t.z = v.z; t.w = v.w;
    __builtin_nontemporal_store(t, (f32x4*)p);
}

// ---------------- Kernel 1: GroupNorm ----------------
__global__ __launch_bounds__(256) void gn_kernel(
    const float* __restrict__ u, const float* __restrict__ gamma,
    const float* __restrict__ beta, float* __restrict__ un)
{
    const int b = blockIdx.x / GROUPS;
    const int g = blockIdx.x % GROUPS;
    const float* base = u + ((size_t)b*D_MODEL + g*CPG) * HW;
    const int NE = CPG * HW; // 16384

    float s = 0.f, s2 = 0.f;
    for (int i = threadIdx.x; i < NE; i += 256) {
        float v = base[i];
        s += v; s2 += v*v;
    }
    for (int off = 32; off; off >>= 1) {
        s  += __shfl_down(s,  off);
        s2 += __shfl_down(s2, off);
    }
    __shared__ float red0[4], red1[4];
    const int wave = threadIdx.x >> 6;
    if ((threadIdx.x & 63) == 0) { red0[wave] = s; red1[wave] = s2; }
    __syncthreads();
    if (threadIdx.x == 0) {
        float a = 0.f, c = 0.f;
        for (int i = 0; i < 4; i++) { a += red0[i]; c += red1[i]; }
        red0[0] = a; red1[0] = c;
    }
    __syncthreads();
    const float mean = red0[0] * (1.f/16384.f);
    const float var  = red1[0] * (1.f/16384.f) - mean*mean;
    const float rstd = rsqrtf(var + 1e-5f);

    for (int i = threadIdx.x; i < NE; i += 256) {
        int c = i >> 10;
        int d = g*CPG + c;
        float v = (base[i] - mean) * rstd;
        un[((size_t)b*D_MODEL + d)*HW + (i & (HW-1))] = v*gamma[d] + beta[d];
    }
}

// ---------------- Kernel 2: A = -exp(log_A_real) ----------------
__global__ __launch_bounds__(256) void aneg_kernel(
    const float* __restrict__ logA, float* __restrict__ aneg)
{
    int i = blockIdx.x*256 + threadIdx.x;
    if (i < D_MODEL*D_STATE) aneg[i] = -expf(logA[i]);
}

// ---------------- Kernel 3: circular 3x3 convs, LDS-staged, 4 co / block ----------------
__global__ __launch_bounds__(256) void conv_kernel(
    const float* __restrict__ un,
    const float* __restrict__ w_delta, const float* __restrict__ b_delta,
    const float* __restrict__ w_B, const float* __restrict__ w_C,
    const float* __restrict__ dt_sp,
    float* __restrict__ delta, float* __restrict__ Bv, float* __restrict__ Cv)
{
    const int bx    = blockIdx.x;
    const int strip = bx & 3;
    const int cog   = (bx >> 2) % 24;
    const int b     = bx / 96;
    const int co0   = cog * 4;
    const int row0  = strip * 8;

    __shared__ float xs[16][10][32];
    __shared__ float wl[4][D_MODEL*9];

    for (int i = threadIdx.x; i < 4*D_MODEL*9; i += 256) {
        const int cl = i / (D_MODEL*9);
        const int rest = i % (D_MODEL*9);
        const int co = co0 + cl;
        const float* w = (co < 64) ? (w_delta + (size_t)co*(D_MODEL*9))
                       : (co < 80) ? (w_B + (size_t)(co-64)*(D_MODEL*9))
                                   : (w_C + (size_t)(co-80)*(D_MODEL*9));
        wl[cl][rest] = w[rest];
    }

    const int ly = threadIdx.x >> 5;
    const int ox = threadIdx.x & 31;
    const int oy = row0 + ly;

    const float* x = un + (size_t)b*D_MODEL*HW;
    float a0 = 0.f, a1 = 0.f, a2 = 0.f, a3 = 0.f;

    for (int c = 0; c < 4; c++) {
        __syncthreads();
        for (int i = threadIdx.x; i < 16*10*32; i += 256) {
            const int ci = i / 320;
            const int rr = (i % 320) >> 5;
            const int xx = i & 31;
            const int gy = (row0 - 1 + rr) & 31;
            xs[ci][rr][xx] = x[(size_t)(c*16 + ci)*HW + (gy << 5) + xx];
        }
        __syncthreads();

        #pragma unroll
        for (int ci = 0; ci < 16; ci++) {
            float v[3][3];
            #pragma unroll
            for (int dy = 0; dy < 3; dy++)
                #pragma unroll
                for (int dx = 0; dx < 3; dx++)
                    v[dy][dx] = xs[ci][ly + dy][(ox + dx + 31) & 31];
            const int cig = c*16 + ci;
            const float* w0 = &wl[0][cig*9];
            const float* w1 = &wl[1][cig*9];
            const float* w2 = &wl[2][cig*9];
            const float* w3 = &wl[3][cig*9];
            #pragma unroll
            for (int t = 0; t < 9; t++) {
                const float xv = v[t/3][t%3];
                a0 = fmaf(xv, w0[t], a0);
                a1 = fmaf(xv, w1[t], a1);
                a2 = fmaf(xv, w2[t], a2);
                a3 = fmaf(xv, w3[t], a3);
            }
        }
    }

    const int p = (oy << 5) + ox;
    const float dtsp = dt_sp[0];
    float accs[4] = {a0, a1, a2, a3};
    #pragma unroll
    for (int cl = 0; cl < 4; cl++) {
        const int co = co0 + cl;
        float acc = accs[cl];
        if (co < 64) {
            acc += b_delta[co] + dtsp;
            float sp = (acc > 15.f) ? acc : log1pf(__expf(acc));
            sp = fminf(fmaxf(sp, 1e-4f), 5.f);
            delta[((size_t)b*D_MODEL + co)*HW + p] = sp;
        } else if (co < 80) {
            Bv[((size_t)b*D_STATE + (co-64))*HW + p] = acc;
        } else {
            Cv[((size_t)b*D_STATE + (co-80))*HW + p] = acc;
        }
    }
}

// ---------------- Kernel 4: main fused state update ----------------
// grid = B*V*D_MODEL (2304) blocks, 256 threads, 4 consecutive pts/thread.
// The per-velocity gather is a 2D circular shift with |shift|<=1: handled by
// row re-addressing (ryo) + in-register x-rotation via __shfl within the
// 8-lane row group (rxo in {0,1,31}); scalar-gather fallback otherwise.
template<int MODE>  // 0: rxo==0, 1: rxo==1 (src[x+1]), 2: rxo==31 (src[x-1])
__device__ __forceinline__ void main_body(
    const float* __restrict__ sp_base, float* __restrict__ sn_base,
    const float* __restrict__ Bv_b, const float* __restrict__ Cv_b,
    const float4 dl, const float4 uu, const float* an,
    float4& y, int srcv, int p0, int laneL, int laneR)
{
    #pragma unroll 4
    for (int n = 0; n < D_STATE; n++) {
        const float4 own = *(const float4*)(sp_base + n*HW + srcv);
        float4 s;
        if (MODE == 0) {
            s = own;
        } else if (MODE == 1) {
            const float nb = __shfl(own.x, laneR, 64);
            s.x = own.y; s.y = own.z; s.z = own.w; s.w = nb;
        } else {
            const float nb = __shfl(own.w, laneL, 64);
            s.x = nb; s.y = own.x; s.z = own.y; s.w = own.z;
        }
        const float4 Bn = *(const float4*)(Bv_b + n*HW);
        const float4 Cn = *(const float4*)(Cv_b + n*HW);
        float4 sn;
        sn.x = fmaf(__expf(dl.x * an[n]), s.x, dl.x * Bn.x * uu.x);
        sn.y = fmaf(__expf(dl.y * an[n]), s.y, dl.y * Bn.y * uu.y);
        sn.z = fmaf(__expf(dl.z * an[n]), s.z, dl.z * Bn.z * uu.z);
        sn.w = fmaf(__expf(dl.w * an[n]), s.w, dl.w * Bn.w * uu.w);
        nt_store4(sn_base + n*HW + p0, sn);
        y.x = fmaf(sn.x, Cn.x, y.x);
        y.y = fmaf(sn.y, Cn.y, y.y);
        y.z = fmaf(sn.z, Cn.z, y.z);
        y.w = fmaf(sn.w, Cn.w, y.w);
    }
}

__global__ __launch_bounds__(256) void main_kernel(
    const float* __restrict__ sprev, const float* __restrict__ ut,
    const float* __restrict__ delta, const float* __restrict__ Bv,
    const float* __restrict__ Cv, const float* __restrict__ aneg,
    const float* __restrict__ Dp, const int* __restrict__ gidx,
    float* __restrict__ ynew, float* __restrict__ snew)
{
    const int blk = blockIdx.x;
    const int d   = blk % D_MODEL;
    const int tmp = blk / D_MODEL;
    const int v   = tmp % V;
    const int b   = tmp / V;

    const int t  = threadIdx.x;
    const int p0 = t * 4;
    const int y0 = p0 >> 5;
    const int x0 = p0 & 31;

    const int gi0 = gidx[v*HW];       // src index of output point 0
    const int ryo = gi0 >> 5;         // row offset: src_y = (y + ryo) & 31
    const int rxo = gi0 & 31;         // col rotation: src_x = (x + rxo) & 31

    const int ys   = (y0 + ryo) & 31;
    const int srcv = (ys << 5) + x0;  // aligned float4 base in source row

    const int lane  = t & 63;
    const int laneL = (lane & ~7) | ((lane + 7) & 7);
    const int laneR = (lane & ~7) | ((lane + 1) & 7);

    const size_t bvd = (((size_t)b*V + v)*D_MODEL + d);
    const float* sp_base = sprev + bvd * D_STATE * HW;
    float* sn_base = snew + bvd * D_STATE * HW;

    const float dpd = Dp[d];
    float an[D_STATE];
    #pragma unroll
    for (int n = 0; n < D_STATE; n++) an[n] = aneg[d*D_STATE + n];

    const float4 dl = *(const float4*)(delta + ((size_t)b*D_MODEL + d)*HW + p0);
    const float4 uu = *(const float4*)(ut    + ((size_t)b*D_MODEL + d)*HW + p0);
    const float* Bv_b = Bv + (size_t)b*D_STATE*HW + p0;
    const float* Cv_b = Cv + (size_t)b*D_STATE*HW + p0;

    float4 y;
    y.x = uu.x * dpd; y.y = uu.y * dpd; y.z = uu.z * dpd; y.w = uu.w * dpd;

    if (rxo == 0) {
        main_body<0>(sp_base, sn_base, Bv_b, Cv_b, dl, uu, an, y, srcv, p0, laneL, laneR);
    } else if (rxo == 1) {
        main_body<1>(sp_base, sn_base, Bv_b, Cv_b, dl, uu, an, y, srcv, p0, laneL, laneR);
    } else if (rxo == 31) {
        main_body<2>(sp_base, sn_base, Bv_b, Cv_b, dl, uu, an, y, srcv, p0, laneL, laneR);
    } else {
        // general fallback: scalar gather (not expected for V_RANGE=1)
        const int4 src4 = *(const int4*)(gidx + v*HW + p0);
        #pragma unroll 4
        for (int n = 0; n < D_STATE; n++) {
            const float* sp_n = sp_base + n*HW;
            const float4 Bn = *(const float4*)(Bv_b + n*HW);
            const float4 Cn = *(const float4*)(Cv_b + n*HW);
            float4 sn;
            sn.x = fmaf(__expf(dl.x * an[n]), sp_n[src4.x], dl.x * Bn.x * uu.x);
            sn.y = fmaf(__expf(dl.y * an[n]), sp_n[src4.y], dl.y * Bn.y * uu.y);
            sn.z = fmaf(__expf(dl.z * an[n]), sp_n[src4.z], dl.z * Bn.z * uu.z);
            sn.w = fmaf(__expf(dl.w * an[n]), sp_n[src4.w], dl.w * Bn.w * uu.w);
            nt_store4(sn_base + n*HW + p0, sn);
            y.x = fmaf(sn.x, Cn.x, y.x);
            y.y = fmaf(sn.y, Cn.y, y.y);
            y.z = fmaf(sn.z, Cn.z, y.z);
            y.w = fmaf(sn.w, Cn.w, y.w);
        }
    }
    nt_store4(ynew + bvd * HW + p0, y);
}

extern "C" void kernel_launch(void* const* d_in, const int* in_sizes, int n_in,
                              void* d_out, int out_size, void* d_ws, size_t ws_size,
                              hipStream_t stream)
{
    const float* u_t       = (const float*)d_in[0];
    const float* s_prev    = (const float*)d_in[1];
    const float* gamma     = (const float*)d_in[2];
    const float* beta      = (const float*)d_in[3];
    const float* w_delta   = (const float*)d_in[4];
    const float* b_delta   = (const float*)d_in[5];
    const float* w_B       = (const float*)d_in[6];
    const float* w_C       = (const float*)d_in[7];
    const float* log_A     = (const float*)d_in[8];
    const float* D_param   = (const float*)d_in[9];
    const float* dt_sp     = (const float*)d_in[10];
    const int*   gidx      = (const int*)d_in[11];

    float* ws = (float*)d_ws;
    float* un    = ws;
    float* delta = un    + (size_t)B*D_MODEL*HW;
    float* Bv    = delta + (size_t)B*D_MODEL*HW;
    float* Cv    = Bv    + (size_t)B*D_STATE*HW;
    float* aneg  = Cv    + (size_t)B*D_STATE*HW;

    float* ynew = (float*)d_out;
    float* snew = ynew + (size_t)B*V*D_MODEL*HW;

    gn_kernel<<<B*GROUPS, 256, 0, stream>>>(u_t, gamma, beta, un);
    aneg_kernel<<<(D_MODEL*D_STATE + 255)/256, 256, 0, stream>>>(log_A, aneg);
    conv_kernel<<<B*96, 256, 0, stream>>>(un, w_delta, b_delta, w_B, w_C, dt_sp,
                                          delta, Bv, Cv);
    main_kernel<<<B*V*D_MODEL, 256, 0, stream>>>(s_prev, u_t, delta, Bv, Cv,
                                                 aneg, D_param, gidx, ynew, snew);
}